// Round 5
// baseline (129.239 us; speedup 1.0000x reference)
//
#include <hip/hip_runtime.h>

typedef _Float16 f16;
typedef __attribute__((ext_vector_type(4))) _Float16 f16x4;
typedef __attribute__((ext_vector_type(8))) _Float16 f16x8;
typedef __attribute__((ext_vector_type(4))) float f32x4;

#define MFMA16(a, b, c) __builtin_amdgcn_mfma_f32_16x16x32_f16((a), (b), (c), 0, 0, 0)

__device__ __forceinline__ void gload_lds16(const void* g, void* l) {
  __builtin_amdgcn_global_load_lds(
      (const __attribute__((address_space(1))) void*)g,
      (__attribute__((address_space(3))) void*)l, 16, 0, 0);
}

// ------- fused prep: convert x -> f16, transpose Wqkv & Wproj -> [N][K] f16 -------
__global__ __launch_bounds__(256) void k_prep(
    const float* __restrict__ x, f16* __restrict__ xb,
    const float* __restrict__ Wq, f16* __restrict__ WqT,
    const float* __restrict__ Wp, f16* __restrict__ WpT) {
  __shared__ float tile[64][65];
  int bid = blockIdx.x;
  if (bid < 768) {
    int i = bid * 256 + threadIdx.x;
#pragma unroll
    for (int it = 0; it < 4; ++it, i += 768 * 256) {
      float4 v = ((const float4*)x)[i];
      f16x4 o;
      o[0] = (f16)v.x; o[1] = (f16)v.y; o[2] = (f16)v.z; o[3] = (f16)v.w;
      ((f16x4*)xb)[i] = o;
    }
    return;
  }
  const float* in; f16* out; int N, n0, k0;
  if (bid < 1200) {
    int t = bid - 768;
    in = Wq; out = WqT; N = 2304;
    n0 = (t % 36) * 64; k0 = (t / 36) * 64;
  } else {
    int t = bid - 1200;
    in = Wp; out = WpT; N = 768;
    n0 = (t % 12) * 64; k0 = (t / 12) * 64;
  }
  int c = threadIdx.x & 63, r4 = threadIdx.x >> 6;
#pragma unroll
  for (int i = 0; i < 16; ++i) {
    int r = i * 4 + r4;
    tile[r][c] = in[(size_t)(k0 + r) * N + n0 + c];
  }
  __syncthreads();
#pragma unroll
  for (int i = 0; i < 16; ++i) {
    int r = i * 4 + r4;
    out[(size_t)(n0 + r) * 768 + k0 + c] = (f16)tile[c][r];
  }
}

// ---------------- 128x128 f16 MFMA GEMM, A[M][K] * BT[N][K]^T ----------------
// mode 0: scatter columns to Q/K [bh][t][d] (f16) and V transposed [bh][d][t]
// mode 1: out[row][col] = acc + bias[col] (fp32)
__global__ __launch_bounds__(256) void k_gemm(
    const f16* __restrict__ A, const f16* __restrict__ BT,
    int M, int N, int K, int mode,
    f16* __restrict__ Qo, f16* __restrict__ Ko, f16* __restrict__ Vt,
    const float* __restrict__ bias, float* __restrict__ out) {
  __shared__ f16 As[128 * 32];
  __shared__ f16 Bs[128 * 32];
  int tid = threadIdx.x;
  int wv = tid >> 6;
  int lane = tid & 63;
  int lr = lane & 15, lc = lane >> 4;
  int m0 = blockIdx.x * 128, n0 = blockIdx.y * 128;
  int wm = (wv >> 1) * 64, wn = (wv & 1) * 64;
  f32x4 acc[4][4] = {};
  int nK = K >> 5;
  for (int kt = 0; kt < nK; ++kt) {
    int k0 = kt << 5;
#pragma unroll
    for (int i = 0; i < 2; ++i) {
      int g = i * 256 + tid;
      gload_lds16(A + (size_t)(m0 + (g >> 2)) * K + k0 + (g & 3) * 8,
                  As + (size_t)(i * 256 + (tid & 192)) * 8);
    }
#pragma unroll
    for (int i = 0; i < 2; ++i) {
      int g = i * 256 + tid;
      gload_lds16(BT + (size_t)(n0 + (g >> 2)) * K + k0 + (g & 3) * 8,
                  Bs + (size_t)(i * 256 + (tid & 192)) * 8);
    }
    __syncthreads();
    f16x8 af[4], bf[4];
#pragma unroll
    for (int mi = 0; mi < 4; ++mi)
      af[mi] = *(const f16x8*)&As[(wm + mi * 16 + lr) * 32 + lc * 8];
#pragma unroll
    for (int ni = 0; ni < 4; ++ni)
      bf[ni] = *(const f16x8*)&Bs[(wn + ni * 16 + lr) * 32 + lc * 8];
#pragma unroll
    for (int mi = 0; mi < 4; ++mi)
#pragma unroll
      for (int ni = 0; ni < 4; ++ni)
        acc[mi][ni] = MFMA16(af[mi], bf[ni], acc[mi][ni]);
    __syncthreads();
  }
  if (mode == 0) {
#pragma unroll
    for (int ni = 0; ni < 4; ++ni) {
      int col = n0 + wn + ni * 16 + lr;
      int s = col / 768;
      int hh = (col - s * 768) >> 6;
      int d = col & 63;
      if (s == 2) {
#pragma unroll
        for (int mi = 0; mi < 4; ++mi) {
          int row0 = m0 + wm + mi * 16 + lc * 4;
          int b = row0 >> 11, t = row0 & 2047;
          f16x4 tv;
#pragma unroll
          for (int r = 0; r < 4; ++r) tv[r] = (f16)acc[mi][ni][r];
          *(f16x4*)&Vt[((size_t)(b * 12 + hh) * 64 + d) * 2048 + t] = tv;
        }
      } else {
        f16* dst = (s == 0) ? Qo : Ko;
#pragma unroll
        for (int mi = 0; mi < 4; ++mi)
#pragma unroll
          for (int r = 0; r < 4; ++r) {
            int row = m0 + wm + mi * 16 + lc * 4 + r;
            int b = row >> 11, t = row & 2047;
            dst[((size_t)(b * 12 + hh) * 2048 + t) * 64 + d] =
                (f16)acc[mi][ni][r];
          }
      }
    }
  } else {
#pragma unroll
    for (int ni = 0; ni < 4; ++ni) {
      int col = n0 + wn + ni * 16 + lr;
      float bv = bias[col];
#pragma unroll
      for (int mi = 0; mi < 4; ++mi)
#pragma unroll
        for (int r = 0; r < 4; ++r) {
          int row = m0 + wm + mi * 16 + lc * 4 + r;
          out[(size_t)row * 768 + col] = acc[mi][ni][r] + bv;
        }
    }
  }
}

// ------------- causal softplus-normalized attention, in-block split-K -------------
// One 256-thread block per (bh, q-tile of 32 rows). 4 waves stride the k-tiles,
// accumulate private O/rowsum, combine via LDS (unioned with the P buffer).
// LDS = max(plds 16K, comb 34K) + rs 0.5K = 35,328 B -> 4 blocks/CU.
__global__ __launch_bounds__(256) void k_attn(const f16* __restrict__ Q,
                                              const f16* __restrict__ K,
                                              const f16* __restrict__ Vt,
                                              f16* __restrict__ Ab) {
  __shared__ __align__(16) char smem[35328];
  f16 (*plds)[2048] = (f16(*)[2048])smem;           // [4][2048], k-loop phase
  float (*comb)[32][68] = (float(*)[32][68])smem;   // [4][32][68], combine phase
  float* rscomb = (float*)(smem + 34816);           // [4][32]
  int tid = threadIdx.x, wv = tid >> 6, lane = tid & 63;
  int lr = lane & 15, lc = lane >> 4;
  int bh = blockIdx.x;
  int qt = 63 - blockIdx.y;  // heavy blocks dispatch first
  int qw = qt * 32;
  int b = bh / 12, h = bh - b * 12;
  const f16* Qp = Q + (size_t)bh * 2048 * 64;
  const f16* Kp = K + (size_t)bh * 2048 * 64;
  const f16* Vp = Vt + (size_t)bh * 64 * 2048;

  const f16 a16 = (f16)0.18033688f;  // 0.125 * log2(e): fold scale into Q
  f16x8 qf[2][2];
#pragma unroll
  for (int mi = 0; mi < 2; ++mi)
#pragma unroll
    for (int kh = 0; kh < 2; ++kh) {
      qf[mi][kh] =
          *(const f16x8*)&Qp[(size_t)(qw + mi * 16 + lr) * 64 + kh * 32 + lc * 8];
      qf[mi][kh] *= a16;
    }

  f32x4 o[2][4] = {};
  float rsl[2][4] = {};
  f16* wb = plds[wv];

  // note: softplus stored UNSCALED by ln2 (w' = max(z,0)+log2(1+2^-|z|));
  // the uniform 1/ln2 factor cancels in w/rowsum.
  auto do_tile = [&](int kb, bool maskit) {
    // hoist V loads: independent of P, latency hides under QK^T + softplus
    f16x8 vf[2][4];
#pragma unroll
    for (int kh = 0; kh < 2; ++kh)
#pragma unroll
      for (int di = 0; di < 4; ++di)
        vf[kh][di] =
            *(const f16x8*)&Vp[(size_t)(di * 16 + lr) * 2048 + kb + kh * 32 + lc * 8];
    f32x4 s[2][4] = {};
#pragma unroll
    for (int ni = 0; ni < 4; ++ni)
#pragma unroll
      for (int kh = 0; kh < 2; ++kh) {
        f16x8 kf =
            *(const f16x8*)&Kp[(size_t)(kb + ni * 16 + lr) * 64 + kh * 32 + lc * 8];
        s[0][ni] = MFMA16(qf[0][kh], kf, s[0][ni]);
        s[1][ni] = MFMA16(qf[1][kh], kf, s[1][ni]);
      }
#pragma unroll
    for (int mi = 0; mi < 2; ++mi)
#pragma unroll
      for (int ni = 0; ni < 4; ++ni) {
        int cb = ni * 16 + lr;
#pragma unroll
        for (int r = 0; r < 4; ++r) {
          int rloc = mi * 16 + lc * 4 + r;
          float z = s[mi][ni][r];
          float t = __builtin_amdgcn_exp2f(-fabsf(z));
          float w = fmaxf(z, 0.f) + __builtin_amdgcn_logf(1.f + t);
          if (maskit) w = (kb + cb <= qw + rloc) ? w : 0.f;
          rsl[mi][r] += w;
          wb[rloc * 64 + (((cb >> 3) ^ (rloc & 7)) << 3) + (cb & 7)] = (f16)w;
        }
      }
#pragma unroll
    for (int kh = 0; kh < 2; ++kh) {
      f16x8 pa[2];
#pragma unroll
      for (int mi = 0; mi < 2; ++mi) {
        int rloc = mi * 16 + lr;
        pa[mi] =
            *(const f16x8*)&wb[rloc * 64 + ((((kh << 2) + lc) ^ (rloc & 7)) << 3)];
      }
#pragma unroll
      for (int di = 0; di < 4; ++di) {
        o[0][di] = MFMA16(pa[0], vf[kh][di], o[0][di]);
        o[1][di] = MFMA16(pa[1], vf[kh][di], o[1][di]);
      }
    }
  };

  // diagonal tile peeled: main loop is maskless
  int dt = qw >> 6;  // index of diagonal tile; ntiles = dt+1
  for (int kt = wv; kt < dt; kt += 4) do_tile(kt << 6, false);
  if (wv == (dt & 3)) do_tile(dt << 6, true);

  // intra-wave rowsum reduce across the 16 lr lanes
#pragma unroll
  for (int mi = 0; mi < 2; ++mi)
#pragma unroll
    for (int r = 0; r < 4; ++r) {
      float p = rsl[mi][r];
      p += __shfl_xor(p, 1);
      p += __shfl_xor(p, 2);
      p += __shfl_xor(p, 4);
      p += __shfl_xor(p, 8);
      rsl[mi][r] = p;
    }

  __syncthreads();  // all waves done with P tiles; smem becomes comb

  // deposit per-wave partials (row pad 68 floats -> ~conflict-free)
#pragma unroll
  for (int mi = 0; mi < 2; ++mi)
#pragma unroll
    for (int r = 0; r < 4; ++r) {
      int row = mi * 16 + lc * 4 + r;
      if (lr == 0) rscomb[wv * 32 + row] = rsl[mi][r];
#pragma unroll
      for (int di = 0; di < 4; ++di)
        comb[wv][row][di * 16 + lr] = o[mi][di][r];
    }
  __syncthreads();

  // cross-wave combine: thread -> (row, 8 d's); normalize; store f16
  int row = tid >> 3, d0 = (tid & 7) << 3;
  float inv = 1.0f / (rscomb[row] + rscomb[32 + row] + rscomb[64 + row] +
                      rscomb[96 + row]);
  float sum[8] = {};
#pragma unroll
  for (int w = 0; w < 4; ++w) {
    float4 a = *(const float4*)&comb[w][row][d0];
    float4 c = *(const float4*)&comb[w][row][d0 + 4];
    sum[0] += a.x; sum[1] += a.y; sum[2] += a.z; sum[3] += a.w;
    sum[4] += c.x; sum[5] += c.y; sum[6] += c.z; sum[7] += c.w;
  }
  f16x8 o8;
#pragma unroll
  for (int e = 0; e < 8; ++e) o8[e] = (f16)(sum[e] * inv);
  *(f16x8*)&Ab[((size_t)b * 2048 + qw + row) * 768 + h * 64 + d0] = o8;
}

// ---------------- host ----------------
extern "C" void kernel_launch(void* const* d_in, const int* in_sizes, int n_in,
                              void* d_out, int out_size, void* d_ws,
                              size_t ws_size, hipStream_t stream) {
  const float* x = (const float*)d_in[0];
  const float* Wqkv = (const float*)d_in[1];
  const float* Wproj = (const float*)d_in[2];
  const float* bproj = (const float*)d_in[3];
  float* out = (float*)d_out;
  char* ws = (char*)d_ws;

  f16* xb     = (f16*)(ws + 0);         // 4096x768
  f16* WqkvT  = (f16*)(ws + 6291456);   // 2304x768
  f16* WprojT = (f16*)(ws + 9830400);   // 768x768
  f16* Qb     = (f16*)(ws + 11010048);  // 24x2048x64
  f16* Kb     = (f16*)(ws + 17301504);  // 24x2048x64
  f16* Vtb    = (f16*)(ws + 23592960);  // 24x64x2048
  f16* Ab     = (f16*)(ws + 29884416);  // 4096x768
  // total 36,175,872 B

  k_prep<<<1344, 256, 0, stream>>>(x, xb, Wqkv, WqkvT, Wproj, WprojT);
  k_gemm<<<dim3(32, 18), 256, 0, stream>>>(xb, WqkvT, 4096, 2304, 768, 0, Qb,
                                           Kb, Vtb, nullptr, nullptr);
  k_attn<<<dim3(24, 64), 256, 0, stream>>>(Qb, Kb, Vtb, Ab);
  k_gemm<<<dim3(32, 6), 256, 0, stream>>>(Ab, WprojT, 4096, 768, 768, 1,
                                          nullptr, nullptr, nullptr, bproj, out);
}